// Round 6
// baseline (896.440 us; speedup 1.0000x reference)
//
#include <hip/hip_runtime.h>
#include <hip/hip_bf16.h>

#define BB 32
#define NN 32768
#define GG 64
#define KK 32
#define DD 384
#define EPSF 1e-5f

__device__ __forceinline__ float rn_add(float a, float b){ return __fadd_rn(a,b); }
__device__ __forceinline__ float rn_sub(float a, float b){ return __fsub_rn(a,b); }
__device__ __forceinline__ float rn_mul(float a, float b){ return __fmul_rn(a,b); }

// monotone float->u32 map: preserves total order of finite floats
__device__ __forceinline__ unsigned fkey(float d){
  unsigned u = __float_as_uint(d);
  return (u & 0x80000000u) ? ~u : (u | 0x80000000u);
}

// ---- module-scope scratch: avoids any assumption about ws_size ------------
__device__ float g_center[BB*GG*3];     // 24 KB
__device__ int   g_knn[BB*GG*KK];       // 256 KB
__device__ float g_w1t[6*64];           // folded, transposed weights
__device__ float g_b1[64];
__device__ float g_w2t[64*128];
__device__ float g_b2[128];
__device__ float g_w3t[128*384];
__device__ float g_b3[384];

// ---------------------------------------------------------------------------
// Weight prep: fold BN (scale,shift) into transposed weights.
// ---------------------------------------------------------------------------
__global__ void k_prep(const float* __restrict__ w1, const float* __restrict__ g1, const float* __restrict__ b1, const float* __restrict__ m1, const float* __restrict__ v1,
                       const float* __restrict__ w2, const float* __restrict__ g2, const float* __restrict__ b2, const float* __restrict__ m2, const float* __restrict__ v2,
                       const float* __restrict__ w3, const float* __restrict__ g3, const float* __restrict__ b3, const float* __restrict__ m3, const float* __restrict__ v3){
  int tid = blockIdx.x * blockDim.x + threadIdx.x;
  int nt  = gridDim.x * blockDim.x;
  for (int e = tid; e < 64*6; e += nt){
    int c = e >> 6, o = e & 63;
    float s = g1[o] * rsqrtf(v1[o] + EPSF);
    g_w1t[e] = w1[o*6 + c] * s;
  }
  for (int o = tid; o < 64; o += nt){
    float s = g1[o] * rsqrtf(v1[o] + EPSF);
    g_b1[o] = b1[o] - m1[o]*s;
  }
  for (int e = tid; e < 64*128; e += nt){
    int c = e >> 7, o = e & 127;
    float s = g2[o] * rsqrtf(v2[o] + EPSF);
    g_w2t[e] = w2[o*64 + c] * s;
  }
  for (int o = tid; o < 128; o += nt){
    float s = g2[o] * rsqrtf(v2[o] + EPSF);
    g_b2[o] = b2[o] - m2[o]*s;
  }
  for (int e = tid; e < 384*128; e += nt){   // e = o*128+c (input-major)
    int o = e >> 7, c = e & 127;
    float s = g3[o] * rsqrtf(v3[o] + EPSF);
    g_w3t[c*384 + o] = w3[e] * s;
  }
  for (int o = tid; o < 384; o += nt){
    float s = g3[o] * rsqrtf(v3[o] + EPSF);
    g_b3[o] = b3[o] - m3[o]*s;
  }
}

// ---------------------------------------------------------------------------
// Farthest point sampling: 1 block per batch, 1024 threads, 32 pts/thread.
// Exact numpy arithmetic, argmax tie-break = lowest index. (validated r3)
// __launch_bounds__(1024, 4): 16 waves/CU = 4 waves/EU -> VGPR cap 128, so
// px/py/dd (96 regs) stay IN REGISTERS. r5's (1024)-only build allocated 64
// VGPR and spilled all three arrays to scratch -> 9.2us/iter, VALUBusy 3.7%.
// ---------------------------------------------------------------------------
__global__ __launch_bounds__(1024, 4) void k_fps(const float* __restrict__ xyz,
                                                 float* __restrict__ outCenter){
  const int b = blockIdx.x;
  const int t = threadIdx.x;
  const float* xb = xyz + (size_t)b*NN*3;

  __shared__ float sz[NN];          // 128 KiB: z coords
  __shared__ float sval[16];
  __shared__ int   sidx[16];
  __shared__ int   sfar;

  float px[32], py[32], dd[32];
  #pragma unroll
  for (int i = 0; i < 32; ++i){
    int p = t + (i << 10);
    px[i] = xb[p*3 + 0];
    py[i] = xb[p*3 + 1];
    sz[p] = xb[p*3 + 2];
    dd[i] = 1e10f;
  }
  __syncthreads();

  int far = 0;
  for (int it = 0; ; ++it){
    float cx = xb[far*3 + 0], cy = xb[far*3 + 1], cz = xb[far*3 + 2];
    if (t == 0){
      float* cw = g_center  + (size_t)(b*GG + it)*3;
      float* co = outCenter + (size_t)(b*GG + it)*3;
      cw[0] = cx; cw[1] = cy; cw[2] = cz;
      co[0] = cx; co[1] = cy; co[2] = cz;
    }
    if (it == GG - 1) break;

    float bv = -1.0f; int bi = 0x7fffffff;
    #pragma unroll
    for (int i = 0; i < 32; ++i){
      int p = t + (i << 10);
      float dx = rn_sub(px[i], cx);
      float dy = rn_sub(py[i], cy);
      float dz = rn_sub(sz[p], cz);
      float s  = rn_add(rn_add(rn_mul(dx,dx), rn_mul(dy,dy)), rn_mul(dz,dz));
      float d  = fminf(dd[i], s);
      dd[i] = d;
      if (d > bv){ bv = d; bi = p; }   // i ascending => idx ascending: strict > keeps first
    }
    #pragma unroll
    for (int off = 32; off >= 1; off >>= 1){
      float ov = __shfl_xor(bv, off);
      int   oi = __shfl_xor(bi, off);
      if (ov > bv || (ov == bv && oi < bi)){ bv = ov; bi = oi; }
    }
    if ((t & 63) == 0){ sval[t >> 6] = bv; sidx[t >> 6] = bi; }
    __syncthreads();
    if (t == 0){
      float v = sval[0]; int ix = sidx[0];
      #pragma unroll
      for (int w = 1; w < 16; ++w){
        float ov = sval[w]; int oi = sidx[w];
        if (ov > v || (ov == v && oi < ix)){ v = ov; ix = oi; }
      }
      sfar = ix;
    }
    __syncthreads();
    far = sfar;
  }
}

// ---------------------------------------------------------------------------
// KNN v3, exact, threshold-based (validated r5):
//  per-thread top-2 -> per-wave sort -> exact global 16th e1 = T (upper bound
//  on true 32nd d2) -> collect d2<=T -> wave 0 exact sort/extract by (d2,idx).
// ---------------------------------------------------------------------------
__global__ __launch_bounds__(1024) void k_knn(const float* __restrict__ xyz){
  const int bg = blockIdx.x;        // b*64+g
  const int b  = bg >> 6;
  const int t  = threadIdx.x;       // 0..1023
  const int w  = t >> 6;            // wave 0..15
  const int ln = t & 63;
  const float* xb = xyz + (size_t)b*NN*3;

  __shared__ unsigned sE[256];               // 16 waves x 16 smallest e1-keys
  __shared__ unsigned long long s_cand[512]; // candidate (key,idx)
  __shared__ int s_cnt;

  const float* cp = g_center + (size_t)bg*3;
  float cx = cp[0], cy = cp[1], cz = cp[2];
  float cn2 = rn_add(rn_add(rn_mul(cx,cx), rn_mul(cy,cy)), rn_mul(cz,cz));

  // ---- 1: d2 of 32 points/lane (identical formula as validated) + top-2 ----
  float d2r[32];
  float e0 = INFINITY, e1 = INFINITY;
  #pragma unroll
  for (int s = 0; s < 32; ++s){
    int i = (w << 11) + (s << 6) + ln;
    float x = xb[i*3], y = xb[i*3+1], z = xb[i*3+2];
    float n2 = rn_add(rn_add(rn_mul(x,x), rn_mul(y,y)), rn_mul(z,z));
    float e  = rn_add(rn_add(rn_mul(cx,x), rn_mul(cy,y)), rn_mul(cz,z));
    float d  = rn_sub(rn_add(cn2, n2), rn_add(e,e));
    d2r[s] = d;
    if (d < e1){ if (d < e0){ e1 = e0; e0 = d; } else e1 = d; }
  }

  // ---- 2: per-wave bitonic sort of e1 keys (ascending across lanes) ----
  {
    unsigned v = fkey(e1);
    #pragma unroll
    for (int k = 2; k <= 64; k <<= 1){
      #pragma unroll
      for (int j = k >> 1; j > 0; j >>= 1){
        unsigned o = (unsigned)__shfl_xor((int)v, j);
        bool keepmin = (((ln & k) == 0) == ((ln & j) == 0));
        unsigned mn = o < v ? o : v;
        unsigned mx = o < v ? v : o;
        v = keepmin ? mn : mx;
      }
    }
    if (ln < 16) sE[w*16 + ln] = v;
  }
  if (t == 0) s_cnt = 0;
  __syncthreads();

  // ---- 3: T = 16th smallest of sE[256] (all waves, redundant/uniform) ----
  unsigned T;
  {
    unsigned a0 = sE[ln*4+0], a1 = sE[ln*4+1], a2 = sE[ln*4+2], a3 = sE[ln*4+3];
    for (int r = 0; r < 16; ++r){
      unsigned m = a0 < a1 ? a0 : a1;
      unsigned m2 = a2 < a3 ? a2 : a3;
      m = m < m2 ? m : m2;
      #pragma unroll
      for (int off = 32; off >= 1; off >>= 1){
        unsigned o = (unsigned)__shfl_xor((int)m, off);
        m = o < m ? o : m;
      }
      T = m;
      unsigned long long msk = __ballot(a0 == m || a1 == m || a2 == m || a3 == m);
      int fl = __ffsll((long long)msk) - 1;
      if (ln == fl){
        if (a0 == m) a0 = 0xFFFFFFFFu;
        else if (a1 == m) a1 = 0xFFFFFFFFu;
        else if (a2 == m) a2 = 0xFFFFFFFFu;
        else a3 = 0xFFFFFFFFu;
      }
    }
  }

  // ---- 4: collect candidates key(d2) <= T ----
  #pragma unroll
  for (int s = 0; s < 32; ++s){
    if (fkey(d2r[s]) <= T){
      int i = (w << 11) + (s << 6) + ln;
      int p = atomicAdd(&s_cnt, 1);
      if (p < 512)
        s_cand[p] = ((unsigned long long)fkey(d2r[s]) << 32) | (unsigned)i;
    }
  }
  __syncthreads();

  // ---- 5: wave 0 selects exact top-32 by (d2, idx) ----
  if (w == 0){
    int C = s_cnt; if (C > 512) C = 512;
    int* kout = g_knn + (size_t)bg*KK;
    if (C <= 64){
      unsigned long long kk = (ln < C) ? s_cand[ln] : ~0ull;
      #pragma unroll
      for (int k = 2; k <= 64; k <<= 1){
        #pragma unroll
        for (int j = k >> 1; j > 0; j >>= 1){
          unsigned long long o = (unsigned long long)__shfl_xor((long long)kk, j);
          bool keepmin = (((ln & k) == 0) == ((ln & j) == 0));
          unsigned long long mn = o < kk ? o : kk;
          unsigned long long mx = o < kk ? kk : o;
          kk = keepmin ? mn : mx;
        }
      }
      if (ln < KK) kout[ln] = (int)(kk & 0xffffffffu);
    } else {
      unsigned long long md[8];
      #pragma unroll
      for (int j = 0; j < 8; ++j){
        int e = ln + (j << 6);
        md[j] = (e < C) ? s_cand[e] : ~0ull;
      }
      for (int r = 0; r < KK; ++r){
        unsigned long long bk = md[0];
        #pragma unroll
        for (int j = 1; j < 8; ++j) if (md[j] < bk) bk = md[j];
        #pragma unroll
        for (int off = 32; off >= 1; off >>= 1){
          unsigned long long o = (unsigned long long)__shfl_xor((long long)bk, off);
          if (o < bk) bk = o;
        }
        #pragma unroll
        for (int j = 0; j < 8; ++j) if (md[j] == bk) md[j] = ~0ull;  // keys unique
        if (ln == 0) kout[r] = (int)(bk & 0xffffffffu);
      }
    }
  }
}

// ---------------------------------------------------------------------------
// MLP 6->64->128->384 + maxpool over K. 1 block per (b,g), 256 threads.
// ---------------------------------------------------------------------------
__global__ __launch_bounds__(256) void k_mlp(const float* __restrict__ xyz,
                                             const float* __restrict__ feat,
                                             float* __restrict__ outPatch){
  const int bg = blockIdx.x;
  const int b  = bg >> 6;
  const int t  = threadIdx.x;
  const float* xb = xyz  + (size_t)b*NN*3;
  const float* fb = feat + (size_t)b*NN*3;

  __shared__ float h0[KK][8];
  __shared__ float h1[KK][68];
  __shared__ float h2[KK][132];
  __shared__ float pmax[4][DD];

  if (t < KK){
    int idx = g_knn[(size_t)bg*KK + t] & (NN - 1);   // defensive clamp (power of 2)
    const float* cp = g_center + (size_t)bg*3;
    h0[t][0] = rn_sub(xb[idx*3+0], cp[0]);
    h0[t][1] = rn_sub(xb[idx*3+1], cp[1]);
    h0[t][2] = rn_sub(xb[idx*3+2], cp[2]);
    h0[t][3] = fb[idx*3+0];
    h0[t][4] = fb[idx*3+1];
    h0[t][5] = fb[idx*3+2];
  }
  __syncthreads();

  { // L1: 32k x 64o, thread = (k, 8 o's)
    int k = t >> 3, ob = (t & 7) * 8;
    float acc[8];
    #pragma unroll
    for (int j = 0; j < 8; ++j) acc[j] = g_b1[ob + j];
    #pragma unroll
    for (int c = 0; c < 6; ++c){
      float a = h0[k][c];
      const float4* wr = (const float4*)(g_w1t + c*64 + ob);
      float4 wa = wr[0], wb = wr[1];
      acc[0] = fmaf(a, wa.x, acc[0]); acc[1] = fmaf(a, wa.y, acc[1]);
      acc[2] = fmaf(a, wa.z, acc[2]); acc[3] = fmaf(a, wa.w, acc[3]);
      acc[4] = fmaf(a, wb.x, acc[4]); acc[5] = fmaf(a, wb.y, acc[5]);
      acc[6] = fmaf(a, wb.z, acc[6]); acc[7] = fmaf(a, wb.w, acc[7]);
    }
    #pragma unroll
    for (int j = 0; j < 8; ++j) h1[k][ob + j] = fmaxf(acc[j], 0.f);
  }
  __syncthreads();

  { // L2: 32k x 128o, thread = (k, 16 o's)
    int k = t >> 3, ob = (t & 7) * 16;
    float acc[16];
    #pragma unroll
    for (int j = 0; j < 16; ++j) acc[j] = g_b2[ob + j];
    for (int c = 0; c < 64; ++c){
      float a = h1[k][c];
      const float4* wr = (const float4*)(g_w2t + c*128 + ob);
      #pragma unroll
      for (int q = 0; q < 4; ++q){
        float4 w4 = wr[q];
        acc[q*4+0] = fmaf(a, w4.x, acc[q*4+0]);
        acc[q*4+1] = fmaf(a, w4.y, acc[q*4+1]);
        acc[q*4+2] = fmaf(a, w4.z, acc[q*4+2]);
        acc[q*4+3] = fmaf(a, w4.w, acc[q*4+3]);
      }
    }
    #pragma unroll
    for (int j = 0; j < 16; ++j) h2[k][ob + j] = fmaxf(acc[j], 0.f);
  }
  __syncthreads();

  { // L3: 32k x 384o + partial max over k. wave wv owns k in [8wv,8wv+8).
    int wv = t >> 6, ln = t & 63;
    float acc[8][6];
    #pragma unroll
    for (int kk = 0; kk < 8; ++kk)
      #pragma unroll
      for (int j = 0; j < 6; ++j) acc[kk][j] = 0.f;
    for (int c = 0; c < 128; ++c){
      float hk[8];
      #pragma unroll
      for (int kk = 0; kk < 8; ++kk) hk[kk] = h2[wv*8 + kk][c];  // broadcast
      float wj[6];
      #pragma unroll
      for (int j = 0; j < 6; ++j) wj[j] = g_w3t[c*384 + ln + 64*j]; // coalesced
      #pragma unroll
      for (int kk = 0; kk < 8; ++kk)
        #pragma unroll
        for (int j = 0; j < 6; ++j) acc[kk][j] = fmaf(hk[kk], wj[j], acc[kk][j]);
    }
    #pragma unroll
    for (int j = 0; j < 6; ++j){
      float m = acc[0][j];
      #pragma unroll
      for (int kk = 1; kk < 8; ++kk) m = fmaxf(m, acc[kk][j]);
      pmax[wv][ln + 64*j] = m;
    }
  }
  __syncthreads();

  if (t < 128){
    #pragma unroll
    for (int s = 0; s < 3; ++s){
      int o = t + 128*s;
      float m = fmaxf(fmaxf(pmax[0][o], pmax[1][o]), fmaxf(pmax[2][o], pmax[3][o]));
      outPatch[(size_t)bg*DD + o] = m + g_b3[o];
    }
  }
}

// ---------------------------------------------------------------------------
extern "C" void kernel_launch(void* const* d_in, const int* in_sizes, int n_in,
                              void* d_out, int out_size, void* d_ws, size_t ws_size,
                              hipStream_t stream){
  (void)in_sizes; (void)n_in; (void)out_size; (void)d_ws; (void)ws_size;
  const float* xyz  = (const float*)d_in[0];
  const float* feat = (const float*)d_in[1];
  const float* w1 = (const float*)d_in[2];
  const float* g1 = (const float*)d_in[3];
  const float* b1 = (const float*)d_in[4];
  const float* m1 = (const float*)d_in[5];
  const float* v1 = (const float*)d_in[6];
  const float* w2 = (const float*)d_in[7];
  const float* g2 = (const float*)d_in[8];
  const float* b2 = (const float*)d_in[9];
  const float* m2 = (const float*)d_in[10];
  const float* v2 = (const float*)d_in[11];
  const float* w3 = (const float*)d_in[12];
  const float* g3 = (const float*)d_in[13];
  const float* b3 = (const float*)d_in[14];
  const float* m3 = (const float*)d_in[15];
  const float* v3 = (const float*)d_in[16];
  float* out = (float*)d_out;

  k_prep<<<64, 256, 0, stream>>>(w1,g1,b1,m1,v1, w2,g2,b2,m2,v2, w3,g3,b3,m3,v3);
  k_fps<<<BB, 1024, 0, stream>>>(xyz, out);
  k_knn<<<BB*GG, 1024, 0, stream>>>(xyz);
  k_mlp<<<BB*GG, 256, 0, stream>>>(xyz, feat, out + (size_t)BB*GG*3);
}

// Round 7
// 892.487 us; speedup vs baseline: 1.0044x; 1.0044x over previous
//
#include <hip/hip_runtime.h>
#include <hip/hip_bf16.h>

#define BB 32
#define NN 32768
#define GG 64
#define KK 32
#define DD 384
#define EPSF 1e-5f

__device__ __forceinline__ float rn_add(float a, float b){ return __fadd_rn(a,b); }
__device__ __forceinline__ float rn_sub(float a, float b){ return __fsub_rn(a,b); }
__device__ __forceinline__ float rn_mul(float a, float b){ return __fmul_rn(a,b); }

// monotone float->u32 map: preserves total order of finite floats
__device__ __forceinline__ unsigned fkey(float d){
  unsigned u = __float_as_uint(d);
  return (u & 0x80000000u) ? ~u : (u | 0x80000000u);
}

#define REP32(X) X(0) X(1) X(2) X(3) X(4) X(5) X(6) X(7) \
                 X(8) X(9) X(10) X(11) X(12) X(13) X(14) X(15) \
                 X(16) X(17) X(18) X(19) X(20) X(21) X(22) X(23) \
                 X(24) X(25) X(26) X(27) X(28) X(29) X(30) X(31)

// ---- module-scope scratch: avoids any assumption about ws_size ------------
__device__ float g_center[BB*GG*3];     // 24 KB
__device__ int   g_knn[BB*GG*KK];       // 256 KB
__device__ float g_w1t[6*64];           // folded, transposed weights
__device__ float g_b1[64];
__device__ float g_w2t[64*128];
__device__ float g_b2[128];
__device__ float g_w3t[128*384];
__device__ float g_b3[384];

// ---------------------------------------------------------------------------
// Weight prep: fold BN (scale,shift) into transposed weights.
// ---------------------------------------------------------------------------
__global__ void k_prep(const float* __restrict__ w1, const float* __restrict__ g1, const float* __restrict__ b1, const float* __restrict__ m1, const float* __restrict__ v1,
                       const float* __restrict__ w2, const float* __restrict__ g2, const float* __restrict__ b2, const float* __restrict__ m2, const float* __restrict__ v2,
                       const float* __restrict__ w3, const float* __restrict__ g3, const float* __restrict__ b3, const float* __restrict__ m3, const float* __restrict__ v3){
  int tid = blockIdx.x * blockDim.x + threadIdx.x;
  int nt  = gridDim.x * blockDim.x;
  for (int e = tid; e < 64*6; e += nt){
    int c = e >> 6, o = e & 63;
    float s = g1[o] * rsqrtf(v1[o] + EPSF);
    g_w1t[e] = w1[o*6 + c] * s;
  }
  for (int o = tid; o < 64; o += nt){
    float s = g1[o] * rsqrtf(v1[o] + EPSF);
    g_b1[o] = b1[o] - m1[o]*s;
  }
  for (int e = tid; e < 64*128; e += nt){
    int c = e >> 7, o = e & 127;
    float s = g2[o] * rsqrtf(v2[o] + EPSF);
    g_w2t[e] = w2[o*64 + c] * s;
  }
  for (int o = tid; o < 128; o += nt){
    float s = g2[o] * rsqrtf(v2[o] + EPSF);
    g_b2[o] = b2[o] - m2[o]*s;
  }
  for (int e = tid; e < 384*128; e += nt){   // e = o*128+c (input-major)
    int o = e >> 7, c = e & 127;
    float s = g3[o] * rsqrtf(v3[o] + EPSF);
    g_w3t[c*384 + o] = w3[e] * s;
  }
  for (int o = tid; o < 384; o += nt){
    float s = g3[o] * rsqrtf(v3[o] + EPSF);
    g_b3[o] = b3[o] - m3[o]*s;
  }
}

// ---------------------------------------------------------------------------
// Farthest point sampling: 1 block per batch, 1024 threads, 32 pts/thread.
// Exact numpy arithmetic, argmax tie-break = lowest index. (validated r3)
//
// r5/r6 POST-MORTEM: array state px[32]/py[32]/dd[32] ended up in SCRATCH
// (VGPR_Count=64, 7.7MB scratch write-back, VALUBusy 3.7%, 580us).
// __launch_bounds__(1024,4) was a no-op => either SROA failed on the
// pre-unroll dynamic indexing, or the allocator pinned a 64-VGPR budget.
// Fix BOTH: (a) named scalars via REP32 macro - no alloca exists, SROA
// irrelevant; (b) amdgpu_waves_per_eu(4,4) pins occupancy target to the
// LDS-forced 4 waves/EU -> 512-VGPR budget, no heuristic spills.
// ---------------------------------------------------------------------------
__global__ __launch_bounds__(1024)
__attribute__((amdgpu_waves_per_eu(4, 4)))
void k_fps(const float* __restrict__ xyz,
           float* __restrict__ outCenter){
  const int b = blockIdx.x;
  const int t = threadIdx.x;
  const float* xb = xyz + (size_t)b*NN*3;

  __shared__ float sz[NN];          // 128 KiB: z coords
  __shared__ float sval[16];
  __shared__ int   sidx[16];
  __shared__ int   sfar;

#define FPS_DECL(i) float px##i, py##i, dd##i;
  REP32(FPS_DECL)
#undef FPS_DECL

#define FPS_INIT(i) { int p = t + (i << 10); \
    px##i = xb[p*3 + 0]; \
    py##i = xb[p*3 + 1]; \
    sz[p] = xb[p*3 + 2]; \
    dd##i = 1e10f; }
  REP32(FPS_INIT)
#undef FPS_INIT
  __syncthreads();

  int far = 0;
  for (int it = 0; ; ++it){
    float cx = xb[far*3 + 0], cy = xb[far*3 + 1], cz = xb[far*3 + 2];
    if (t == 0){
      float* cw = g_center  + (size_t)(b*GG + it)*3;
      float* co = outCenter + (size_t)(b*GG + it)*3;
      cw[0] = cx; cw[1] = cy; cw[2] = cz;
      co[0] = cx; co[1] = cy; co[2] = cz;
    }
    if (it == GG - 1) break;

    float bv = -1.0f; int bi = 0x7fffffff;
    // ascending slot order => ascending point index => strict > keeps the
    // FIRST (lowest-index) maximum, matching numpy argmax.
#define FPS_UPD(i) { \
    float dx = rn_sub(px##i, cx); \
    float dy = rn_sub(py##i, cy); \
    float dz = rn_sub(sz[t + (i << 10)], cz); \
    float s  = rn_add(rn_add(rn_mul(dx,dx), rn_mul(dy,dy)), rn_mul(dz,dz)); \
    float d  = fminf(dd##i, s); \
    dd##i = d; \
    if (d > bv){ bv = d; bi = t + (i << 10); } }
    REP32(FPS_UPD)
#undef FPS_UPD

    #pragma unroll
    for (int off = 32; off >= 1; off >>= 1){
      float ov = __shfl_xor(bv, off);
      int   oi = __shfl_xor(bi, off);
      if (ov > bv || (ov == bv && oi < bi)){ bv = ov; bi = oi; }
    }
    if ((t & 63) == 0){ sval[t >> 6] = bv; sidx[t >> 6] = bi; }
    __syncthreads();
    if (t == 0){
      float v = sval[0]; int ix = sidx[0];
      #pragma unroll
      for (int w = 1; w < 16; ++w){
        float ov = sval[w]; int oi = sidx[w];
        if (ov > v || (ov == v && oi < ix)){ v = ov; ix = oi; }
      }
      sfar = ix;
    }
    __syncthreads();
    far = sfar;
  }
}

// ---------------------------------------------------------------------------
// KNN v3, exact, threshold-based (validated r5):
//  per-thread top-2 -> per-wave sort -> exact global 16th e1 = T (upper bound
//  on true 32nd d2) -> collect d2<=T -> wave 0 exact sort/extract by (d2,idx).
// ---------------------------------------------------------------------------
__global__ __launch_bounds__(1024) void k_knn(const float* __restrict__ xyz){
  const int bg = blockIdx.x;        // b*64+g
  const int b  = bg >> 6;
  const int t  = threadIdx.x;       // 0..1023
  const int w  = t >> 6;            // wave 0..15
  const int ln = t & 63;
  const float* xb = xyz + (size_t)b*NN*3;

  __shared__ unsigned sE[256];               // 16 waves x 16 smallest e1-keys
  __shared__ unsigned long long s_cand[512]; // candidate (key,idx)
  __shared__ int s_cnt;

  const float* cp = g_center + (size_t)bg*3;
  float cx = cp[0], cy = cp[1], cz = cp[2];
  float cn2 = rn_add(rn_add(rn_mul(cx,cx), rn_mul(cy,cy)), rn_mul(cz,cz));

  // ---- 1: d2 of 32 points/lane (identical formula as validated) + top-2 ----
  float d2r[32];
  float e0 = INFINITY, e1 = INFINITY;
  #pragma unroll
  for (int s = 0; s < 32; ++s){
    int i = (w << 11) + (s << 6) + ln;
    float x = xb[i*3], y = xb[i*3+1], z = xb[i*3+2];
    float n2 = rn_add(rn_add(rn_mul(x,x), rn_mul(y,y)), rn_mul(z,z));
    float e  = rn_add(rn_add(rn_mul(cx,x), rn_mul(cy,y)), rn_mul(cz,z));
    float d  = rn_sub(rn_add(cn2, n2), rn_add(e,e));
    d2r[s] = d;
    if (d < e1){ if (d < e0){ e1 = e0; e0 = d; } else e1 = d; }
  }

  // ---- 2: per-wave bitonic sort of e1 keys (ascending across lanes) ----
  {
    unsigned v = fkey(e1);
    #pragma unroll
    for (int k = 2; k <= 64; k <<= 1){
      #pragma unroll
      for (int j = k >> 1; j > 0; j >>= 1){
        unsigned o = (unsigned)__shfl_xor((int)v, j);
        bool keepmin = (((ln & k) == 0) == ((ln & j) == 0));
        unsigned mn = o < v ? o : v;
        unsigned mx = o < v ? v : o;
        v = keepmin ? mn : mx;
      }
    }
    if (ln < 16) sE[w*16 + ln] = v;
  }
  if (t == 0) s_cnt = 0;
  __syncthreads();

  // ---- 3: T = 16th smallest of sE[256] (all waves, redundant/uniform) ----
  unsigned T;
  {
    unsigned a0 = sE[ln*4+0], a1 = sE[ln*4+1], a2 = sE[ln*4+2], a3 = sE[ln*4+3];
    for (int r = 0; r < 16; ++r){
      unsigned m = a0 < a1 ? a0 : a1;
      unsigned m2 = a2 < a3 ? a2 : a3;
      m = m < m2 ? m : m2;
      #pragma unroll
      for (int off = 32; off >= 1; off >>= 1){
        unsigned o = (unsigned)__shfl_xor((int)m, off);
        m = o < m ? o : m;
      }
      T = m;
      unsigned long long msk = __ballot(a0 == m || a1 == m || a2 == m || a3 == m);
      int fl = __ffsll((long long)msk) - 1;
      if (ln == fl){
        if (a0 == m) a0 = 0xFFFFFFFFu;
        else if (a1 == m) a1 = 0xFFFFFFFFu;
        else if (a2 == m) a2 = 0xFFFFFFFFu;
        else a3 = 0xFFFFFFFFu;
      }
    }
  }

  // ---- 4: collect candidates key(d2) <= T ----
  #pragma unroll
  for (int s = 0; s < 32; ++s){
    if (fkey(d2r[s]) <= T){
      int i = (w << 11) + (s << 6) + ln;
      int p = atomicAdd(&s_cnt, 1);
      if (p < 512)
        s_cand[p] = ((unsigned long long)fkey(d2r[s]) << 32) | (unsigned)i;
    }
  }
  __syncthreads();

  // ---- 5: wave 0 selects exact top-32 by (d2, idx) ----
  if (w == 0){
    int C = s_cnt; if (C > 512) C = 512;
    int* kout = g_knn + (size_t)bg*KK;
    if (C <= 64){
      unsigned long long kk = (ln < C) ? s_cand[ln] : ~0ull;
      #pragma unroll
      for (int k = 2; k <= 64; k <<= 1){
        #pragma unroll
        for (int j = k >> 1; j > 0; j >>= 1){
          unsigned long long o = (unsigned long long)__shfl_xor((long long)kk, j);
          bool keepmin = (((ln & k) == 0) == ((ln & j) == 0));
          unsigned long long mn = o < kk ? o : kk;
          unsigned long long mx = o < kk ? kk : o;
          kk = keepmin ? mn : mx;
        }
      }
      if (ln < KK) kout[ln] = (int)(kk & 0xffffffffu);
    } else {
      unsigned long long md[8];
      #pragma unroll
      for (int j = 0; j < 8; ++j){
        int e = ln + (j << 6);
        md[j] = (e < C) ? s_cand[e] : ~0ull;
      }
      for (int r = 0; r < KK; ++r){
        unsigned long long bk = md[0];
        #pragma unroll
        for (int j = 1; j < 8; ++j) if (md[j] < bk) bk = md[j];
        #pragma unroll
        for (int off = 32; off >= 1; off >>= 1){
          unsigned long long o = (unsigned long long)__shfl_xor((long long)bk, off);
          if (o < bk) bk = o;
        }
        #pragma unroll
        for (int j = 0; j < 8; ++j) if (md[j] == bk) md[j] = ~0ull;  // keys unique
        if (ln == 0) kout[r] = (int)(bk & 0xffffffffu);
      }
    }
  }
}

// ---------------------------------------------------------------------------
// MLP 6->64->128->384 + maxpool over K. 1 block per (b,g), 256 threads.
// ---------------------------------------------------------------------------
__global__ __launch_bounds__(256) void k_mlp(const float* __restrict__ xyz,
                                             const float* __restrict__ feat,
                                             float* __restrict__ outPatch){
  const int bg = blockIdx.x;
  const int b  = bg >> 6;
  const int t  = threadIdx.x;
  const float* xb = xyz  + (size_t)b*NN*3;
  const float* fb = feat + (size_t)b*NN*3;

  __shared__ float h0[KK][8];
  __shared__ float h1[KK][68];
  __shared__ float h2[KK][132];
  __shared__ float pmax[4][DD];

  if (t < KK){
    int idx = g_knn[(size_t)bg*KK + t] & (NN - 1);   // defensive clamp (power of 2)
    const float* cp = g_center + (size_t)bg*3;
    h0[t][0] = rn_sub(xb[idx*3+0], cp[0]);
    h0[t][1] = rn_sub(xb[idx*3+1], cp[1]);
    h0[t][2] = rn_sub(xb[idx*3+2], cp[2]);
    h0[t][3] = fb[idx*3+0];
    h0[t][4] = fb[idx*3+1];
    h0[t][5] = fb[idx*3+2];
  }
  __syncthreads();

  { // L1: 32k x 64o, thread = (k, 8 o's)
    int k = t >> 3, ob = (t & 7) * 8;
    float acc[8];
    #pragma unroll
    for (int j = 0; j < 8; ++j) acc[j] = g_b1[ob + j];
    #pragma unroll
    for (int c = 0; c < 6; ++c){
      float a = h0[k][c];
      const float4* wr = (const float4*)(g_w1t + c*64 + ob);
      float4 wa = wr[0], wb = wr[1];
      acc[0] = fmaf(a, wa.x, acc[0]); acc[1] = fmaf(a, wa.y, acc[1]);
      acc[2] = fmaf(a, wa.z, acc[2]); acc[3] = fmaf(a, wa.w, acc[3]);
      acc[4] = fmaf(a, wb.x, acc[4]); acc[5] = fmaf(a, wb.y, acc[5]);
      acc[6] = fmaf(a, wb.z, acc[6]); acc[7] = fmaf(a, wb.w, acc[7]);
    }
    #pragma unroll
    for (int j = 0; j < 8; ++j) h1[k][ob + j] = fmaxf(acc[j], 0.f);
  }
  __syncthreads();

  { // L2: 32k x 128o, thread = (k, 16 o's)
    int k = t >> 3, ob = (t & 7) * 16;
    float acc[16];
    #pragma unroll
    for (int j = 0; j < 16; ++j) acc[j] = g_b2[ob + j];
    for (int c = 0; c < 64; ++c){
      float a = h1[k][c];
      const float4* wr = (const float4*)(g_w2t + c*128 + ob);
      #pragma unroll
      for (int q = 0; q < 4; ++q){
        float4 w4 = wr[q];
        acc[q*4+0] = fmaf(a, w4.x, acc[q*4+0]);
        acc[q*4+1] = fmaf(a, w4.y, acc[q*4+1]);
        acc[q*4+2] = fmaf(a, w4.z, acc[q*4+2]);
        acc[q*4+3] = fmaf(a, w4.w, acc[q*4+3]);
      }
    }
    #pragma unroll
    for (int j = 0; j < 16; ++j) h2[k][ob + j] = fmaxf(acc[j], 0.f);
  }
  __syncthreads();

  { // L3: 32k x 384o + partial max over k. wave wv owns k in [8wv,8wv+8).
    int wv = t >> 6, ln = t & 63;
    float acc[8][6];
    #pragma unroll
    for (int kk = 0; kk < 8; ++kk)
      #pragma unroll
      for (int j = 0; j < 6; ++j) acc[kk][j] = 0.f;
    for (int c = 0; c < 128; ++c){
      float hk[8];
      #pragma unroll
      for (int kk = 0; kk < 8; ++kk) hk[kk] = h2[wv*8 + kk][c];  // broadcast
      float wj[6];
      #pragma unroll
      for (int j = 0; j < 6; ++j) wj[j] = g_w3t[c*384 + ln + 64*j]; // coalesced
      #pragma unroll
      for (int kk = 0; kk < 8; ++kk)
        #pragma unroll
        for (int j = 0; j < 6; ++j) acc[kk][j] = fmaf(hk[kk], wj[j], acc[kk][j]);
    }
    #pragma unroll
    for (int j = 0; j < 6; ++j){
      float m = acc[0][j];
      #pragma unroll
      for (int kk = 1; kk < 8; ++kk) m = fmaxf(m, acc[kk][j]);
      pmax[wv][ln + 64*j] = m;
    }
  }
  __syncthreads();

  if (t < 128){
    #pragma unroll
    for (int s = 0; s < 3; ++s){
      int o = t + 128*s;
      float m = fmaxf(fmaxf(pmax[0][o], pmax[1][o]), fmaxf(pmax[2][o], pmax[3][o]));
      outPatch[(size_t)bg*DD + o] = m + g_b3[o];
    }
  }
}

// ---------------------------------------------------------------------------
extern "C" void kernel_launch(void* const* d_in, const int* in_sizes, int n_in,
                              void* d_out, int out_size, void* d_ws, size_t ws_size,
                              hipStream_t stream){
  (void)in_sizes; (void)n_in; (void)out_size; (void)d_ws; (void)ws_size;
  const float* xyz  = (const float*)d_in[0];
  const float* feat = (const float*)d_in[1];
  const float* w1 = (const float*)d_in[2];
  const float* g1 = (const float*)d_in[3];
  const float* b1 = (const float*)d_in[4];
  const float* m1 = (const float*)d_in[5];
  const float* v1 = (const float*)d_in[6];
  const float* w2 = (const float*)d_in[7];
  const float* g2 = (const float*)d_in[8];
  const float* b2 = (const float*)d_in[9];
  const float* m2 = (const float*)d_in[10];
  const float* v2 = (const float*)d_in[11];
  const float* w3 = (const float*)d_in[12];
  const float* g3 = (const float*)d_in[13];
  const float* b3 = (const float*)d_in[14];
  const float* m3 = (const float*)d_in[15];
  const float* v3 = (const float*)d_in[16];
  float* out = (float*)d_out;

  k_prep<<<64, 256, 0, stream>>>(w1,g1,b1,m1,v1, w2,g2,b2,m2,v2, w3,g3,b3,m3,v3);
  k_fps<<<BB, 1024, 0, stream>>>(xyz, out);
  k_knn<<<BB*GG, 1024, 0, stream>>>(xyz);
  k_mlp<<<BB*GG, 256, 0, stream>>>(xyz, feat, out + (size_t)BB*GG*3);
}